// Round 1
// baseline (231.574 us; speedup 1.0000x reference)
//
#include <hip/hip_runtime.h>
#include <hip/hip_bf16.h>
#include <math.h>

typedef __attribute__((ext_vector_type(8))) short short8;
typedef __attribute__((ext_vector_type(4))) short short4v;
typedef __attribute__((ext_vector_type(4))) float float4v;
typedef unsigned short ushort_t;

constexpr int NPTS = 32768;  // B*N
constexpr int NN   = 16384;  // points per batch
constexpr int KK   = 32;     // neighbors
constexpr int CC   = 128;    // channels
constexpr int GRP  = 16;     // points per block -> grid 2048
constexpr int SR   = 136;    // res LDS row stride (shorts): 272 B -> 2-way banks (free)
#define LN_EPS 1e-5f
#define MFMA   __builtin_amdgcn_mfma_f32_16x16x32_bf16

// d_ws layout (bytes)
constexpr size_t WS_WP   = 0;        // W' swizzled: 20*128*8 bf16 = 40960 B
constexpr size_t WS_WO   = 40960;    // w_out swizzled: 128*128 bf16 = 32768 B
constexpr size_t WS_BE   = 73728;    // beff: 128 f32 = 512 B
constexpr size_t WS_PG   = 74240;    // PG = w_pos@w_gcm: 10*128 f32 = 5120 B
constexpr size_t WS_FB   = 79360;    // features bf16: 32768*128*2 = 8388608 B
constexpr size_t WS_NEED = WS_FB + (size_t)NPTS * CC * 2;

__device__ __forceinline__ short f2bs(float x) {
    return (short)__builtin_bit_cast(unsigned short, __float2bfloat16(x));
}
__device__ __forceinline__ float bs2f(ushort_t u) {
    return __uint_as_float(((unsigned)u) << 16);
}

// ---------------- prep stage 1: fold (one 128-dot per thread, fully parallel) ----------------
__global__ __launch_bounds__(128) void prep_fold(
    const float* __restrict__ w_pos, const float* __restrict__ b_pos,
    const float* __restrict__ w_gcm, const float* __restrict__ b_gcm,
    float* __restrict__ wsPG, float* __restrict__ wsBeff)
{
    const int c = threadIdx.x, g = blockIdx.x;
    if (g < 10) {
        float s = 0.f;
        #pragma unroll
        for (int r = 0; r < 128; ++r) s += w_pos[g * 128 + r] * w_gcm[r * 128 + c];
        wsPG[g * 128 + c] = s;
    } else {
        float s = b_gcm[c];
        #pragma unroll
        for (int r = 0; r < 128; ++r) s += b_pos[r] * w_gcm[r * 128 + c];
        wsBeff[c] = s;
    }
}

// ---------------- prep stage 2: swizzles + feature f32->bf16 convert (all parallel) ----------------
__global__ __launch_bounds__(256) void prep_pack(
    const float* __restrict__ features, const float* __restrict__ w_gcm,
    const float* __restrict__ w_out, const float* __restrict__ wsPG,
    short* __restrict__ wsWp, short* __restrict__ wsWo, ushort_t* __restrict__ featbf,
    int do_convert)
{
    const int t = threadIdx.x, blk = blockIdx.x;
    if (blk < 512) {
        if (!do_convert) return;
        const int base = blk * 2048 + t;
        #pragma unroll
        for (int i = 0; i < 8; ++i) {
            const int f4 = base + i * 256;
            const float4 a = ((const float4*)features)[f4];
            short4v v; v[0]=f2bs(a.x); v[1]=f2bs(a.y); v[2]=f2bs(a.z); v[3]=f2bs(a.w);
            ((short4v*)featbf)[f4] = v;
        }
        return;
    }
    if (blk == 512) {          // W' region k<128: packed (g,n,j), k=8g+j
        #pragma unroll 4
        for (int e = t; e < 16 * 128 * 8; e += 256) {
            const int j = e & 7, n = (e >> 3) & 127, g = e >> 10;
            wsWp[e] = f2bs(w_gcm[(g * 8 + j) * 128 + n]);
        }
        return;
    }
    if (blk == 513) {          // W' region k in [128,160): PG rows then zeros
        #pragma unroll 4
        for (int e2 = t; e2 < 4 * 128 * 8; e2 += 256) {
            const int e = 16 * 128 * 8 + e2;
            const int j = e & 7, n = (e >> 3) & 127, g = e >> 10;
            const int k = g * 8 + j;
            wsWp[e] = (k < 138) ? f2bs(wsPG[(k - 128) * 128 + n]) : (short)0;
        }
        return;
    }
    // blk == 514: w_out swizzle
    #pragma unroll 4
    for (int e = t; e < 128 * 128; e += 256) {
        const int j = e & 7, n = (e >> 3) & 127, g = e >> 10;
        wsWo[e] = f2bs(w_out[(g * 8 + j) * 128 + n]);
    }
}

// ---------------- main kernel: barrier-free, register-direct gather ----------------
// Each wave owns 32 output cols (col0, col0+16). A-fragments for the MFMA are
// gathered straight from featbf into registers (lane = row l&15, k-chunk = ks*4+quad),
// geo tile is built in-register. No LDS staging of A, no in-loop __syncthreads.
// 2-deep pipeline: idx two points ahead (LDS), fragments one point ahead (global).
template<int FB>   // FB=1: bf16 featbf path; FB=0: f32 fallback (no workspace)
__global__ __launch_bounds__(256) void bridge_main(
    const float* __restrict__ points, const float* __restrict__ features,
    const int*   __restrict__ gidx,
    const short* __restrict__ wsWp, const short* __restrict__ wsWo,
    const float* __restrict__ wsBeff, const ushort_t* __restrict__ featbf,
    const float* __restrict__ b_out, const float* __restrict__ ln_g,
    const float* __restrict__ ln_b,
    float* __restrict__ out)
{
    __shared__ int   sIdx[GRP * KK];     // 2 KB
    __shared__ short sRes[GRP * SR];     // 4.25 KB
    __shared__ float sPS[4][GRP], sPQ[4][GRP];

    const int t = threadIdx.x, wv = t >> 6, lane = t & 63;
    const int quad = (lane >> 4) & 3, m = lane & 15;
    const int g0 = blockIdx.x * GRP;
    const int nbase = (g0 >= NN) ? NN : 0;    // batch base (GRP divides NN)
    const int col0 = wv * 32 + m;

    // ---- stage neighbor indices (coalesced, once) ----
    sIdx[t]       = gidx[(size_t)g0 * KK + t];
    sIdx[t + 256] = gidx[(size_t)g0 * KK + t + 256];

    // ---- B fragments + per-column constants ----
    short8 bWp[5][2];
    #pragma unroll
    for (int ks = 0; ks < 5; ++ks)
        #pragma unroll
        for (int ntl = 0; ntl < 2; ++ntl)
            bWp[ks][ntl] = *((const short8*)wsWp + ((ks * 4 + quad) * 128 + col0 + ntl * 16));
    const float beffv[2] = { wsBeff[col0], wsBeff[col0 + 16] };

    __syncthreads();   // the ONLY barrier before the tail

    // ---- pipeline state (all indices static after full unroll) ----
    int      kn[2][2];        // [buf][0]=row m neighbor, [1]=row m+16 neighbor
    short8   fA[2][4][2];     // [buf][ks][rowgrp] A-fragments
    float    geoR[2][9];      // [buf][c0..2, n0xyz, n1xyz]  (lanes<32 only)
    ushort_t residU[2][2];
    float    residF[2][2];

    auto ldIdx = [&](int p, int buf) {
        kn[buf][0] = nbase + sIdx[p * KK + m];
        kn[buf][1] = nbase + sIdx[p * KK + 16 + m];
    };

    auto ldFrag = [&](int p, int buf) {
        const int pt = g0 + p;
        if constexpr (FB) {
            const short8* b0 = (const short8*)(featbf + (size_t)kn[buf][0] * CC);
            const short8* b1 = (const short8*)(featbf + (size_t)kn[buf][1] * CC);
            #pragma unroll
            for (int ks = 0; ks < 4; ++ks) {
                fA[buf][ks][0] = b0[ks * 4 + quad];
                fA[buf][ks][1] = b1[ks * 4 + quad];
            }
            if (quad == 0) {
                residU[buf][0] = featbf[(size_t)pt * CC + col0];
                residU[buf][1] = featbf[(size_t)pt * CC + col0 + 16];
            }
        } else {
            const float4* c0 = (const float4*)(features + (size_t)kn[buf][0] * CC);
            const float4* c1 = (const float4*)(features + (size_t)kn[buf][1] * CC);
            #pragma unroll
            for (int ks = 0; ks < 4; ++ks) {
                const float4 x0 = c0[ks * 8 + quad * 2], x1 = c0[ks * 8 + quad * 2 + 1];
                const float4 y0 = c1[ks * 8 + quad * 2], y1 = c1[ks * 8 + quad * 2 + 1];
                short8 v;
                v[0]=f2bs(x0.x); v[1]=f2bs(x0.y); v[2]=f2bs(x0.z); v[3]=f2bs(x0.w);
                v[4]=f2bs(x1.x); v[5]=f2bs(x1.y); v[6]=f2bs(x1.z); v[7]=f2bs(x1.w);
                fA[buf][ks][0] = v;
                v[0]=f2bs(y0.x); v[1]=f2bs(y0.y); v[2]=f2bs(y0.z); v[3]=f2bs(y0.w);
                v[4]=f2bs(y1.x); v[5]=f2bs(y1.y); v[6]=f2bs(y1.z); v[7]=f2bs(y1.w);
                fA[buf][ks][1] = v;
            }
            if (quad == 0) {
                residF[buf][0] = features[(size_t)pt * CC + col0];
                residF[buf][1] = features[(size_t)pt * CC + col0 + 16];
            }
        }
        if (quad < 2) {   // lanes 0..31 hold the nonzero geo k-chunks
            const float* pc = points + (size_t)pt * 3;
            const float* p0 = points + (size_t)kn[buf][0] * 3;
            const float* p1 = points + (size_t)kn[buf][1] * 3;
            geoR[buf][0] = pc[0]; geoR[buf][1] = pc[1]; geoR[buf][2] = pc[2];
            geoR[buf][3] = p0[0]; geoR[buf][4] = p0[1]; geoR[buf][5] = p0[2];
            geoR[buf][6] = p1[0]; geoR[buf][7] = p1[1]; geoR[buf][8] = p1[2];
        }
    };

    auto compute = [&](int p, int buf) {
        float4v acc[2][2] = {};
        #pragma unroll
        for (int ks = 0; ks < 4; ++ks) {
            acc[0][0] = MFMA(fA[buf][ks][0], bWp[ks][0], acc[0][0], 0, 0, 0);
            acc[0][1] = MFMA(fA[buf][ks][0], bWp[ks][1], acc[0][1], 0, 0, 0);
            acc[1][0] = MFMA(fA[buf][ks][1], bWp[ks][0], acc[1][0], 0, 0, 0);
            acc[1][1] = MFMA(fA[buf][ks][1], bWp[ks][1], acc[1][1], 0, 0, 0);
        }
        // geo fragments in-register: [cx,cy,cz,gx,gy,gz,dx,dy | dz,dist | 0...]
        short8 ga0 = (short8)0, ga1 = (short8)0;
        if (quad < 2) {
            const float cx  = geoR[buf][0], cy  = geoR[buf][1], cz  = geoR[buf][2];
            const float axx = geoR[buf][3], ayy = geoR[buf][4], azz = geoR[buf][5];
            const float bxx = geoR[buf][6], byy = geoR[buf][7], bzz = geoR[buf][8];
            const float d0x = axx - cx, d0y = ayy - cy, d0z = azz - cz;
            const float d1x = bxx - cx, d1y = byy - cy, d1z = bzz - cz;
            const float ds0 = sqrtf(d0x * d0x + d0y * d0y + d0z * d0z);
            const float ds1 = sqrtf(d1x * d1x + d1y * d1y + d1z * d1z);
            if (quad == 0) {
                ga0[0]=f2bs(cx);  ga0[1]=f2bs(cy);  ga0[2]=f2bs(cz);
                ga0[3]=f2bs(axx); ga0[4]=f2bs(ayy); ga0[5]=f2bs(azz);
                ga0[6]=f2bs(d0x); ga0[7]=f2bs(d0y);
                ga1[0]=f2bs(cx);  ga1[1]=f2bs(cy);  ga1[2]=f2bs(cz);
                ga1[3]=f2bs(bxx); ga1[4]=f2bs(byy); ga1[5]=f2bs(bzz);
                ga1[6]=f2bs(d1x); ga1[7]=f2bs(d1y);
            } else {
                ga0[0]=f2bs(d0z); ga0[1]=f2bs(ds0);
                ga1[0]=f2bs(d1z); ga1[1]=f2bs(ds1);
            }
        }
        acc[0][0] = MFMA(ga0, bWp[4][0], acc[0][0], 0, 0, 0);
        acc[0][1] = MFMA(ga0, bWp[4][1], acc[0][1], 0, 0, 0);
        acc[1][0] = MFMA(ga1, bWp[4][0], acc[1][0], 0, 0, 0);
        acc[1][1] = MFMA(ga1, bWp[4][1], acc[1][1], 0, 0, 0);

        // ---- relu+max-pool over 32 neighbors, residual, stash res ----
        #pragma unroll
        for (int ntl = 0; ntl < 2; ++ntl) {
            float v = acc[0][ntl][0];
            #pragma unroll
            for (int rr = 1; rr < 4; ++rr) v = fmaxf(v, acc[0][ntl][rr]);
            #pragma unroll
            for (int rr = 0; rr < 4; ++rr) v = fmaxf(v, acc[1][ntl][rr]);
            v = fmaxf(v, __shfl_xor(v, 16));
            v = fmaxf(v, __shfl_xor(v, 32));
            v = fmaxf(v + beffv[ntl], 0.f);
            if (quad == 0) {
                float fc;
                if constexpr (FB) fc = bs2f(residU[buf][ntl]);
                else              fc = residF[buf][ntl];
                sRes[p * SR + col0 + ntl * 16] = f2bs(v + fc);
            }
        }
    };

    // ---- prologue ----
    ldIdx(0, 0);
    ldFrag(0, 0);
    ldIdx(1, 1);

    // ---- barrier-free main loop (fully unrolled: all buffer indices static) ----
    #pragma unroll
    for (int p = 0; p < GRP; ++p) {
        const int buf = p & 1;
        if (p + 1 < GRP) ldFrag(p + 1, buf ^ 1);   // issue next point's gather early
        if (p + 2 < GRP) ldIdx(p + 2, buf);        // idx two ahead (kn[buf] already consumed)
        compute(p, buf);
    }

    __syncthreads();

    // ---- out projection: res(16x128) @ w_out(128x128) ----
    short8 bWo[4][2];
    #pragma unroll
    for (int ks = 0; ks < 4; ++ks)
        #pragma unroll
        for (int ntl = 0; ntl < 2; ++ntl)
            bWo[ks][ntl] = *((const short8*)wsWo + ((ks * 4 + quad) * 128 + col0 + ntl * 16));

    const short* rm = sRes + m * SR;
    float4v acc2[2] = {};
    #pragma unroll
    for (int ks = 0; ks < 4; ++ks) {
        const short8 a = *(const short8*)(rm + ks * 32 + quad * 8);
        acc2[0] = MFMA(a, bWo[ks][0], acc2[0], 0, 0, 0);
        acc2[1] = MFMA(a, bWo[ks][1], acc2[1], 0, 0, 0);
    }

    const float boutv[2] = { b_out[col0], b_out[col0 + 16] };
    const float lngv[2]  = { ln_g[col0], ln_g[col0 + 16] };
    const float lnbv[2]  = { ln_b[col0], ln_b[col0 + 16] };

    #pragma unroll
    for (int r = 0; r < 4; ++r) {
        const float o0 = acc2[0][r] + boutv[0];
        const float o1 = acc2[1][r] + boutv[1];
        float ss = o0 + o1, qq = o0 * o0 + o1 * o1;
        #pragma unroll
        for (int d = 1; d < 16; d <<= 1) { ss += __shfl_xor(ss, d); qq += __shfl_xor(qq, d); }
        if (m == 0) { sPS[wv][quad * 4 + r] = ss; sPQ[wv][quad * 4 + r] = qq; }
    }
    __syncthreads();

    #pragma unroll
    for (int r = 0; r < 4; ++r) {
        const int R = quad * 4 + r;
        const float S = sPS[0][R] + sPS[1][R] + sPS[2][R] + sPS[3][R];
        const float Q = sPQ[0][R] + sPQ[1][R] + sPQ[2][R] + sPQ[3][R];
        const float mu  = S * (1.f / 128.f);
        const float var = fmaxf(Q * (1.f / 128.f) - mu * mu, 0.f);
        const float rstd = rsqrtf(var + LN_EPS);
        const float o0 = acc2[0][r] + boutv[0];
        const float o1 = acc2[1][r] + boutv[1];
        const size_t base = (size_t)(g0 + R) * CC;
        out[base + col0]      = fmaxf((o0 - mu) * rstd * lngv[0] + lnbv[0], 0.f);
        out[base + col0 + 16] = fmaxf((o1 - mu) * rstd * lngv[1] + lnbv[1], 0.f);
    }
}

extern "C" void kernel_launch(void* const* d_in, const int* in_sizes, int n_in,
                              void* d_out, int out_size, void* d_ws, size_t ws_size,
                              hipStream_t stream) {
    const float* points   = (const float*)d_in[0];
    const float* features = (const float*)d_in[1];
    const int*   gidx     = (const int*)  d_in[2];
    const float* w_pos    = (const float*)d_in[3];
    const float* b_pos    = (const float*)d_in[4];
    const float* w_gcm    = (const float*)d_in[5];
    const float* b_gcm    = (const float*)d_in[6];
    const float* w_out    = (const float*)d_in[7];
    const float* b_out    = (const float*)d_in[8];
    const float* ln_g     = (const float*)d_in[9];
    const float* ln_b     = (const float*)d_in[10];
    float* out = (float*)d_out;

    char* ws = (char*)d_ws;
    short*    wsWp   = (short*)(ws + WS_WP);
    short*    wsWo   = (short*)(ws + WS_WO);
    float*    wsBeff = (float*)(ws + WS_BE);
    float*    wsPG   = (float*)(ws + WS_PG);
    ushort_t* featbf = (ushort_t*)(ws + WS_FB);

    const bool use_bf = (ws_size >= WS_NEED);

    hipLaunchKernelGGL(prep_fold, dim3(11), dim3(128), 0, stream,
                       w_pos, b_pos, w_gcm, b_gcm, wsPG, wsBeff);
    hipLaunchKernelGGL(prep_pack, dim3(515), dim3(256), 0, stream,
                       features, w_gcm, w_out, wsPG, wsWp, wsWo, featbf,
                       use_bf ? 1 : 0);
    if (use_bf) {
        hipLaunchKernelGGL((bridge_main<1>), dim3(NPTS / GRP), dim3(256), 0, stream,
                           points, features, gidx, wsWp, wsWo, wsBeff, featbf,
                           b_out, ln_g, ln_b, out);
    } else {
        hipLaunchKernelGGL((bridge_main<0>), dim3(NPTS / GRP), dim3(256), 0, stream,
                           points, features, gidx, wsWp, wsWo, wsBeff, featbf,
                           b_out, ln_g, ln_b, out);
    }
}

// Round 2
// 163.336 us; speedup vs baseline: 1.4178x; 1.4178x over previous
//
#include <hip/hip_runtime.h>
#include <hip/hip_bf16.h>
#include <math.h>

typedef __attribute__((ext_vector_type(8))) short short8;
typedef __attribute__((ext_vector_type(4))) short short4v;
typedef __attribute__((ext_vector_type(4))) float float4v;
typedef unsigned short ushort_t;

constexpr int NPTS = 32768;  // B*N
constexpr int NN   = 16384;  // points per batch
constexpr int KK   = 32;     // neighbors
constexpr int CC   = 128;    // channels
constexpr int GRP  = 16;     // points per block -> grid 2048
constexpr int SG2  = 24;     // geo LDS row stride (shorts): 48 B, 16B-aligned subrows, 2-way banks (free)
constexpr int SR   = 136;    // res LDS row stride (shorts): 272 B -> 2-way banks (free)
#define LN_EPS 1e-5f
#define MFMA   __builtin_amdgcn_mfma_f32_16x16x32_bf16

// d_ws layout (bytes)
constexpr size_t WS_WP   = 0;        // W' swizzled: 20*128*8 bf16 = 40960 B
constexpr size_t WS_WO   = 40960;    // w_out swizzled: 128*128 bf16 = 32768 B
constexpr size_t WS_BE   = 73728;    // beff: 128 f32 = 512 B
constexpr size_t WS_PG   = 74240;    // PG = w_pos@w_gcm: 10*128 f32 = 5120 B
constexpr size_t WS_FB   = 79360;    // features bf16: 32768*128*2 = 8388608 B
constexpr size_t WS_NEED = WS_FB + (size_t)NPTS * CC * 2;

__device__ __forceinline__ short f2bs(float x) {
    return (short)__builtin_bit_cast(unsigned short, __float2bfloat16(x));
}
__device__ __forceinline__ float bs2f(ushort_t u) {
    return __uint_as_float(((unsigned)u) << 16);
}

// ---------------- prep stage 1: fold (one 128-dot per thread, fully parallel) ----------------
__global__ __launch_bounds__(128) void prep_fold(
    const float* __restrict__ w_pos, const float* __restrict__ b_pos,
    const float* __restrict__ w_gcm, const float* __restrict__ b_gcm,
    float* __restrict__ wsPG, float* __restrict__ wsBeff)
{
    const int c = threadIdx.x, g = blockIdx.x;
    if (g < 10) {
        float s = 0.f;
        #pragma unroll
        for (int r = 0; r < 128; ++r) s += w_pos[g * 128 + r] * w_gcm[r * 128 + c];
        wsPG[g * 128 + c] = s;
    } else {
        float s = b_gcm[c];
        #pragma unroll
        for (int r = 0; r < 128; ++r) s += b_pos[r] * w_gcm[r * 128 + c];
        wsBeff[c] = s;
    }
}

// ---------------- prep stage 2: swizzles + feature f32->bf16 convert (all parallel) ----------------
__global__ __launch_bounds__(256) void prep_pack(
    const float* __restrict__ features, const float* __restrict__ w_gcm,
    const float* __restrict__ w_out, const float* __restrict__ wsPG,
    short* __restrict__ wsWp, short* __restrict__ wsWo, ushort_t* __restrict__ featbf,
    int do_convert)
{
    const int t = threadIdx.x, blk = blockIdx.x;
    if (blk < 512) {
        if (!do_convert) return;
        const int base = blk * 2048 + t;
        #pragma unroll
        for (int i = 0; i < 8; ++i) {
            const int f4 = base + i * 256;
            const float4 a = ((const float4*)features)[f4];
            short4v v; v[0]=f2bs(a.x); v[1]=f2bs(a.y); v[2]=f2bs(a.z); v[3]=f2bs(a.w);
            ((short4v*)featbf)[f4] = v;
        }
        return;
    }
    if (blk == 512) {          // W' region k<128: packed (g,n,j), k=8g+j
        #pragma unroll 4
        for (int e = t; e < 16 * 128 * 8; e += 256) {
            const int j = e & 7, n = (e >> 3) & 127, g = e >> 10;
            wsWp[e] = f2bs(w_gcm[(g * 8 + j) * 128 + n]);
        }
        return;
    }
    if (blk == 513) {          // W' region k in [128,160): PG rows then zeros
        #pragma unroll 4
        for (int e2 = t; e2 < 4 * 128 * 8; e2 += 256) {
            const int e = 16 * 128 * 8 + e2;
            const int j = e & 7, n = (e >> 3) & 127, g = e >> 10;
            const int k = g * 8 + j;
            wsWp[e] = (k < 138) ? f2bs(wsPG[(k - 128) * 128 + n]) : (short)0;
        }
        return;
    }
    // blk == 514: w_out swizzle
    #pragma unroll 4
    for (int e = t; e < 128 * 128; e += 256) {
        const int j = e & 7, n = (e >> 3) & 127, g = e >> 10;
        wsWo[e] = f2bs(w_out[(g * 8 + j) * 128 + n]);
    }
}

// ---------------- main kernel: DMA gather + counted-wait deep pipeline ----------------
// Depth-3 prefetch, 4 sA buffers, 3 sG buffers, raw s_barrier + lgkmcnt(0) per point
// (never vmcnt(0) in steady state: DMA stays in flight across barriers, T3/T4).
// The geo_store ds_write's auto vmcnt-wait transitively guarantees (in-order vmcnt)
// that DMA(p+1) landed before barrier(p+1) with ~2 iterations of slack.
template<int FB>   // FB=1: bf16 featbf workspace path (DMA); FB=0: f32 fallback (reg-staged, slow)
__global__ __launch_bounds__(256, 3) void bridge_main(
    const float* __restrict__ points, const float* __restrict__ features,
    const int*   __restrict__ gidx,
    const short* __restrict__ wsWp, const short* __restrict__ wsWo,
    const float* __restrict__ wsBeff, const ushort_t* __restrict__ featbf,
    const float* __restrict__ b_out, const float* __restrict__ ln_g,
    const float* __restrict__ ln_b,
    float* __restrict__ out)
{
    __shared__ short sA[4][KK * CC];      // gathered features, 4-deep, XOR-chunk-swizzled (32 KB)
    __shared__ short sG[3][KK * SG2];     // geo k-chunks 128..143 (quads 0,1), 3-deep (4.5 KB)
    __shared__ short sRes[GRP * SR];      // pooled+resid rows (4.25 KB)
    __shared__ short sResF[GRP * CC];     // center features bf16, hoisted resid (4 KB)
    __shared__ int   sIdx[GRP * KK];      // 512 neighbor indices (2 KB)
    __shared__ float sCtr[GRP * 3];       // center xyz (192 B)
    __shared__ float sPS[4][GRP], sPQ[4][GRP];

    const int t = threadIdx.x, wv = t >> 6, lane = t & 63;
    const int quad = (lane >> 4) & 3, m = lane & 15;
    const int g0 = blockIdx.x * GRP;
    const int nbase = (g0 >= NN) ? NN : 0;    // batch base (GRP divides NN)
    const int col0 = wv * 32 + m;

    // ---- prologue staging ----
    sIdx[t]       = gidx[(size_t)g0 * KK + t];
    sIdx[t + 256] = gidx[(size_t)g0 * KK + t + 256];
    if (t < GRP * 3) sCtr[t] = points[(size_t)g0 * 3 + t];
    if constexpr (FB) {
        // hoisted residual features: 16 rows x 256B contiguous -> one DMA per wave
        const ushort_t* rs = featbf + (size_t)g0 * CC + (wv * 64 + lane) * 8;
        short* rd = sResF + wv * 512;
        __builtin_amdgcn_global_load_lds((const __attribute__((address_space(1))) void*)rs,
                                         (__attribute__((address_space(3))) void*)rd, 16, 0, 0);
    } else {
        const float* fs = features + (size_t)g0 * CC + t * 8;
        short8 v;
        #pragma unroll
        for (int i = 0; i < 8; ++i) v[i] = f2bs(fs[i]);
        *(short8*)&sResF[t * 8] = v;
    }

    // ---- B fragments + per-column constants ----
    short8 bWp[5][2];
    #pragma unroll
    for (int ks = 0; ks < 5; ++ks)
        #pragma unroll
        for (int ntl = 0; ntl < 2; ++ntl)
            bWp[ks][ntl] = *((const short8*)wsWp + ((ks * 4 + quad) * 128 + col0 + ntl * 16));
    const float beffv[2] = { wsBeff[col0], wsBeff[col0 + 16] };

    __syncthreads();   // sIdx/sCtr/sResF visible (one-time full drain)

    // ---- gather lane mapping: 16 lanes per row, XOR chunk swizzle ----
    const int r0 = wv * 4 + (lane >> 4);  // 0..15 (rows r0 and r0+16)
    const int pc = lane & 15;             // physical 16B chunk
    const int gc = pc ^ r0;               // logical chunk; swizzle key aliases mod 16

    float geoS[3][3];                     // neighbor xyz reg slots (lanes<8), depth-3

    auto geo_load = [&](int q) {
        if (lane < 8) {
            const int j = wv * 8 + lane;
            const int kng = nbase + sIdx[q * KK + j];
            const float* pp = points + (size_t)kng * 3;
            const int s = q % 3;
            geoS[s][0] = pp[0]; geoS[s][1] = pp[1]; geoS[s][2] = pp[2];
        }
    };
    auto issue_dma = [&](int q) {
        const int buf = q & 3;
        const int kn0 = nbase + sIdx[q * KK + r0];
        const int kn1 = nbase + sIdx[q * KK + r0 + 16];
        if constexpr (FB) {
            const ushort_t* gp0 = featbf + (size_t)kn0 * CC + gc * 8;
            const ushort_t* gp1 = featbf + (size_t)kn1 * CC + gc * 8;
            short* l0 = &sA[buf][(wv * 4) * CC];          // wave-uniform; lane i -> +i*16B
            short* l1 = &sA[buf][(wv * 4 + 16) * CC];
            __builtin_amdgcn_global_load_lds((const __attribute__((address_space(1))) void*)gp0,
                                             (__attribute__((address_space(3))) void*)l0, 16, 0, 0);
            __builtin_amdgcn_global_load_lds((const __attribute__((address_space(1))) void*)gp1,
                                             (__attribute__((address_space(3))) void*)l1, 16, 0, 0);
        } else {
            // fallback: immediate load+convert+store (stalls, but correct without workspace)
            const float4* f0 = (const float4*)(features + (size_t)kn0 * CC + gc * 8);
            const float4* f1 = (const float4*)(features + (size_t)kn1 * CC + gc * 8);
            const float4 a = f0[0], b = f0[1], c = f1[0], d = f1[1];
            short8 v;
            v[0]=f2bs(a.x); v[1]=f2bs(a.y); v[2]=f2bs(a.z); v[3]=f2bs(a.w);
            v[4]=f2bs(b.x); v[5]=f2bs(b.y); v[6]=f2bs(b.z); v[7]=f2bs(b.w);
            *(short8*)&sA[buf][r0 * CC + pc * 8] = v;
            v[0]=f2bs(c.x); v[1]=f2bs(c.y); v[2]=f2bs(c.z); v[3]=f2bs(c.w);
            v[4]=f2bs(d.x); v[5]=f2bs(d.y); v[6]=f2bs(d.z); v[7]=f2bs(d.w);
            *(short8*)&sA[buf][(r0 + 16) * CC + pc * 8] = v;
        }
    };
    auto geo_store = [&](int q) {
        if (lane < 8) {
            const int j = wv * 8 + lane, s = q % 3, b = q % 3;
            const float cx = sCtr[q * 3], cy = sCtr[q * 3 + 1], cz = sCtr[q * 3 + 2];
            const float gx = geoS[s][0], gy = geoS[s][1], gz = geoS[s][2];
            const float dx = gx - cx, dy = gy - cy, dz = gz - cz;
            const float dist = sqrtf(dx * dx + dy * dy + dz * dz);
            short8 v0, v1 = (short8)0;
            v0[0]=f2bs(cx); v0[1]=f2bs(cy); v0[2]=f2bs(cz);
            v0[3]=f2bs(gx); v0[4]=f2bs(gy); v0[5]=f2bs(gz);
            v0[6]=f2bs(dx); v0[7]=f2bs(dy);
            v1[0]=f2bs(dz); v1[1]=f2bs(dist);
            *(short8*)&sG[b][j * SG2 + 0] = v0;
            *(short8*)&sG[b][j * SG2 + 8] = v1;
        }
    };

    // loop-invariant A-fragment offsets (shorts)
    int offA[4];
    #pragma unroll
    for (int ks = 0; ks < 4; ++ks) offA[ks] = m * CC + (((ks * 4 + quad) ^ m) * 8);
    const int offG = m * SG2 + quad * 8;

    auto compute = [&](int p) {
        const short* ab = sA[p & 3];
        const short* ag = sG[p % 3];
        float4v acc[2][2] = {};
        #pragma unroll
        for (int ks = 0; ks < 4; ++ks) {
            const short8 a0 = *(const short8*)(ab + offA[ks]);
            const short8 a1 = *(const short8*)(ab + offA[ks] + 16 * CC);
            acc[0][0] = MFMA(a0, bWp[ks][0], acc[0][0], 0, 0, 0);
            acc[0][1] = MFMA(a0, bWp[ks][1], acc[0][1], 0, 0, 0);
            acc[1][0] = MFMA(a1, bWp[ks][0], acc[1][0], 0, 0, 0);
            acc[1][1] = MFMA(a1, bWp[ks][1], acc[1][1], 0, 0, 0);
        }
        short8 ga0 = (short8)0, ga1 = (short8)0;
        if (quad < 2) {   // quads 2,3 are the zero k-region: skip LDS, feed zero regs
            ga0 = *(const short8*)(ag + offG);
            ga1 = *(const short8*)(ag + offG + 16 * SG2);
        }
        acc[0][0] = MFMA(ga0, bWp[4][0], acc[0][0], 0, 0, 0);
        acc[0][1] = MFMA(ga0, bWp[4][1], acc[0][1], 0, 0, 0);
        acc[1][0] = MFMA(ga1, bWp[4][0], acc[1][0], 0, 0, 0);
        acc[1][1] = MFMA(ga1, bWp[4][1], acc[1][1], 0, 0, 0);

        // ---- relu+max-pool over 32 neighbors, residual (from LDS), stash res ----
        #pragma unroll
        for (int ntl = 0; ntl < 2; ++ntl) {
            float v = acc[0][ntl][0];
            #pragma unroll
            for (int rr = 1; rr < 4; ++rr) v = fmaxf(v, acc[0][ntl][rr]);
            #pragma unroll
            for (int rr = 0; rr < 4; ++rr) v = fmaxf(v, acc[1][ntl][rr]);
            v = fmaxf(v, __shfl_xor(v, 16));
            v = fmaxf(v, __shfl_xor(v, 32));
            v = fmaxf(v + beffv[ntl], 0.f);
            if (quad == 0) {
                const float fc = bs2f((ushort_t)sResF[p * CC + col0 + ntl * 16]);
                sRes[p * SR + col0 + ntl * 16] = f2bs(v + fc);
            }
        }
    };

    // ---- ramp: fill 3-deep pipeline ----
    geo_load(0); issue_dma(0);
    geo_load(1); issue_dma(1);
    geo_load(2); issue_dma(2);
    geo_store(0);   // auto-waits its geo loads (one-time prologue stall)
    geo_store(1);
    __syncthreads();   // drains DMA(0..2) once; barrier(0)

    // ---- steady loop: 1 raw barrier per point, DMA in flight across it ----
    #pragma unroll
    for (int p = 0; p < GRP; ++p) {
        if (p > 0) {
            if (p == GRP - 1) asm volatile("s_waitcnt vmcnt(0)" ::: "memory");  // no later geo_store covers DMA(15)
            asm volatile("s_waitcnt lgkmcnt(0)" ::: "memory");  // own ds_writes visible to peers
            __builtin_amdgcn_s_barrier();
        }
        __builtin_amdgcn_sched_barrier(0);   // nothing crosses the barrier
        if (p + 3 < GRP) { geo_load(p + 3); issue_dma(p + 3); }
        compute(p);
        if (p + 2 < GRP) geo_store(p + 2);   // auto vmcnt here transitively fences DMA(p+1)
    }

    __syncthreads();

    // ---- out projection: res(16x128) @ w_out(128x128) ----
    short8 bWo[4][2];
    #pragma unroll
    for (int ks = 0; ks < 4; ++ks)
        #pragma unroll
        for (int ntl = 0; ntl < 2; ++ntl)
            bWo[ks][ntl] = *((const short8*)wsWo + ((ks * 4 + quad) * 128 + col0 + ntl * 16));

    const short* rm = sRes + m * SR;
    float4v acc2[2] = {};
    #pragma unroll
    for (int ks = 0; ks < 4; ++ks) {
        const short8 a = *(const short8*)(rm + ks * 32 + quad * 8);
        acc2[0] = MFMA(a, bWo[ks][0], acc2[0], 0, 0, 0);
        acc2[1] = MFMA(a, bWo[ks][1], acc2[1], 0, 0, 0);
    }

    const float boutv[2] = { b_out[col0], b_out[col0 + 16] };
    const float lngv[2]  = { ln_g[col0], ln_g[col0 + 16] };
    const float lnbv[2]  = { ln_b[col0], ln_b[col0 + 16] };

    #pragma unroll
    for (int r = 0; r < 4; ++r) {
        const float o0 = acc2[0][r] + boutv[0];
        const float o1 = acc2[1][r] + boutv[1];
        float ss = o0 + o1, qq = o0 * o0 + o1 * o1;
        #pragma unroll
        for (int d = 1; d < 16; d <<= 1) { ss += __shfl_xor(ss, d); qq += __shfl_xor(qq, d); }
        if (m == 0) { sPS[wv][quad * 4 + r] = ss; sPQ[wv][quad * 4 + r] = qq; }
    }
    __syncthreads();

    #pragma unroll
    for (int r = 0; r < 4; ++r) {
        const int R = quad * 4 + r;
        const float S = sPS[0][R] + sPS[1][R] + sPS[2][R] + sPS[3][R];
        const float Q = sPQ[0][R] + sPQ[1][R] + sPQ[2][R] + sPQ[3][R];
        const float mu  = S * (1.f / 128.f);
        const float var = fmaxf(Q * (1.f / 128.f) - mu * mu, 0.f);
        const float rstd = rsqrtf(var + LN_EPS);
        const float o0 = acc2[0][r] + boutv[0];
        const float o1 = acc2[1][r] + boutv[1];
        const size_t base = (size_t)(g0 + R) * CC;
        out[base + col0]      = fmaxf((o0 - mu) * rstd * lngv[0] + lnbv[0], 0.f);
        out[base + col0 + 16] = fmaxf((o1 - mu) * rstd * lngv[1] + lnbv[1], 0.f);
    }
}

extern "C" void kernel_launch(void* const* d_in, const int* in_sizes, int n_in,
                              void* d_out, int out_size, void* d_ws, size_t ws_size,
                              hipStream_t stream) {
    const float* points   = (const float*)d_in[0];
    const float* features = (const float*)d_in[1];
    const int*   gidx     = (const int*)  d_in[2];
    const float* w_pos    = (const float*)d_in[3];
    const float* b_pos    = (const float*)d_in[4];
    const float* w_gcm    = (const float*)d_in[5];
    const float* b_gcm    = (const float*)d_in[6];
    const float* w_out    = (const float*)d_in[7];
    const float* b_out    = (const float*)d_in[8];
    const float* ln_g     = (const float*)d_in[9];
    const float* ln_b     = (const float*)d_in[10];
    float* out = (float*)d_out;

    char* ws = (char*)d_ws;
    short*    wsWp   = (short*)(ws + WS_WP);
    short*    wsWo   = (short*)(ws + WS_WO);
    float*    wsBeff = (float*)(ws + WS_BE);
    float*    wsPG   = (float*)(ws + WS_PG);
    ushort_t* featbf = (ushort_t*)(ws + WS_FB);

    const bool use_bf = (ws_size >= WS_NEED);

    hipLaunchKernelGGL(prep_fold, dim3(11), dim3(128), 0, stream,
                       w_pos, b_pos, w_gcm, b_gcm, wsPG, wsBeff);
    hipLaunchKernelGGL(prep_pack, dim3(515), dim3(256), 0, stream,
                       features, w_gcm, w_out, wsPG, wsWp, wsWo, featbf,
                       use_bf ? 1 : 0);
    if (use_bf) {
        hipLaunchKernelGGL((bridge_main<1>), dim3(NPTS / GRP), dim3(256), 0, stream,
                           points, features, gidx, wsWp, wsWo, wsBeff, featbf,
                           b_out, ln_g, ln_b, out);
    } else {
        hipLaunchKernelGGL((bridge_main<0>), dim3(NPTS / GRP), dim3(256), 0, stream,
                           points, features, gidx, wsWp, wsWo, wsBeff, featbf,
                           b_out, ln_g, ln_b, out);
    }
}